// Round 7
// baseline (299.349 us; speedup 1.0000x reference)
//
#include <hip/hip_runtime.h>
#include <hip/hip_fp16.h>

#define NLAB 30000
#define HID  1024
#define NB   256
#define NE   (NLAB - 1)

#define BLOCKS 512               // 2 per CU, one scheduling round, all identical
#define WAVES_PER_BLK 16
#define TOT_WAVES (BLOCKS * WAVES_PER_BLK)   // 8192
#define NL4 (NLAB / 4)           // 7500 float4 per row
#define HALF4 (NL4 / 2)          // 3750
#define EHALF 15000              // edge split point between the 2 row-sharers
#define EGRP  (TOT_WAVES / 4)    // 2048 edge-residue groups

// float block reduce, 1024 threads (16 waves)
__device__ __forceinline__ float blockReduceSum1024(float v) {
#pragma unroll
    for (int off = 32; off > 0; off >>= 1)
        v += __shfl_down(v, off, 64);
    __shared__ float smem[16];
    const int lane = threadIdx.x & 63;
    const int wid  = threadIdx.x >> 6;
    __syncthreads();
    if (lane == 0) smem[wid] = v;
    __syncthreads();
    float r = 0.f;
    if (threadIdx.x == 0) {
#pragma unroll
        for (int i = 0; i < 16; ++i) r += smem[i];
    }
    return r;
}

__device__ __forceinline__ double blockReduceSumD256(double v) {
#pragma unroll
    for (int off = 32; off > 0; off >>= 1)
        v += __shfl_down(v, off, 64);
    __shared__ double smem[4];
    const int lane = threadIdx.x & 63;
    const int wid  = threadIdx.x >> 6;
    __syncthreads();
    if (lane == 0) smem[wid] = v;
    __syncthreads();
    double r = 0.0;
    if (threadIdx.x == 0) r = smem[0] + smem[1] + smem[2] + smem[3];
    return r;
}

__device__ __forceinline__ float sqdiff4(const float4 a, const float4 b) {
    const float dx = a.x - b.x, dy = a.y - b.y;
    const float dz = a.z - b.z, dw = a.w - b.w;
    return dx * dx + dy * dy + dz * dz + dw * dw;
}

// ---------------------------------------------------------------------------
// All 512 blocks identical:
//   row phase: block pair (r=bid>>1, h=bid&1) stages the FULL fp16 sigmoid
//     row in LDS (60 KB), BCE over its half of targets, prob_reg over its
//     half of edges from LDS.
//   rec phase: work item = (edge, quarter-row). Wave gw owns quarter q=gw&3
//     of edges e = (gw>>2) + k*2048, k=0..14 (k=14 masked). 4 strands per
//     macro-iter = 8 INDEPENDENT 1KB loads live at once (32 data VGPRs).
//     gw made wave-uniform via readfirstlane -> scalar index loads (lgkmcnt)
//     + saddr-form row loads; only vmcnt on the critical path.
// ---------------------------------------------------------------------------
__global__ __launch_bounds__(1024, 8)
void fused_kernel(const float4* __restrict__ lg4,
                  const float4* __restrict__ tg4,
                  const float4* __restrict__ p4,
                  const int* __restrict__ pidx,
                  const int* __restrict__ cidx,
                  double* __restrict__ slots) {
    __shared__ __half sprob[NLAB];
    const int tid  = threadIdx.x;
    const int bid  = blockIdx.x;
    const int lane = tid & 63;
    const int r    = bid >> 1;    // batch row
    const int h    = bid & 1;     // which half of targets/edges

    float bces = 0.f, recs = 0.f, ps = 0.f;

    // ---- row phase: sigmoid staging (full row) + BCE (half) ----
    {
        const float4* lrow = lg4 + (size_t)r * NL4;
        const float4* trow = tg4 + (size_t)r * NL4;
        const int tlo = h * HALF4, thi = tlo + HALF4;
        for (int i = tid; i < NL4; i += 1024) {
            const float4 l = lrow[i];
            // e = exp(-|l|); inv = 1/(1+e) = sigmoid(|l|)
            const float e0 = __expf(-fabsf(l.x)), i0 = __frcp_rn(1.f + e0);
            const float e1 = __expf(-fabsf(l.y)), i1 = __frcp_rn(1.f + e1);
            const float e2 = __expf(-fabsf(l.z)), i2 = __frcp_rn(1.f + e2);
            const float e3 = __expf(-fabsf(l.w)), i3 = __frcp_rn(1.f + e3);
            const float s0 = l.x > 0.f ? i0 : 1.f - i0;
            const float s1 = l.y > 0.f ? i1 : 1.f - i1;
            const float s2 = l.z > 0.f ? i2 : 1.f - i2;
            const float s3 = l.w > 0.f ? i3 : 1.f - i3;
            sprob[4 * i + 0] = __float2half(s0);
            sprob[4 * i + 1] = __float2half(s1);
            sprob[4 * i + 2] = __float2half(s2);
            sprob[4 * i + 3] = __float2half(s3);
            if (i >= tlo && i < thi) {
                const float4 t = trow[i];
                // softplus(l) = max(l,0) - log(sigmoid(|l|))
                bces += fmaxf(l.x, 0.f) - __logf(i0) - l.x * t.x;
                bces += fmaxf(l.y, 0.f) - __logf(i1) - l.y * t.y;
                bces += fmaxf(l.z, 0.f) - __logf(i2) - l.z * t.z;
                bces += fmaxf(l.w, 0.f) - __logf(i3) - l.w * t.w;
            }
        }
        __syncthreads();
        // ---- prob_reg over our half of the edges, from LDS ----
        const int elo = h ? EHALF : 0;
        const int ehi = h ? NE : EHALF;
        for (int e = elo + tid; e < ehi; e += 1024) {
            const float d = __half2float(sprob[cidx[e]]) -
                            __half2float(sprob[pidx[e]]);
            ps += d > 0.f ? d : 0.f;
        }
    }

    // ---- rec phase: 4-strand quarter-row gather ----
    {
        const int gw    = __builtin_amdgcn_readfirstlane(
                              bid * WAVES_PER_BLK + (tid >> 6));
        const int q     = gw & 3;       // quarter of the row this wave covers
        const int ebase = gw >> 2;      // edge residue group, 0..2047
        const float4* pq = p4 + q * 64 + lane;   // quarter+lane pre-offset

        // k = 0..11: always valid (max e = 2047 + 11*2048 = 24575 < NE)
        for (int k0 = 0; k0 < 12; k0 += 4) {
            const int e0 = ebase + (k0 + 0) * EGRP;
            const int e1 = ebase + (k0 + 1) * EGRP;
            const int e2 = ebase + (k0 + 2) * EGRP;
            const int e3 = ebase + (k0 + 3) * EGRP;
            const int p0 = pidx[e0], c0 = cidx[e0];
            const int p1 = pidx[e1], c1 = cidx[e1];
            const int p2 = pidx[e2], c2 = cidx[e2];
            const int p3 = pidx[e3], c3 = cidx[e3];
            const float4 A0 = pq[(size_t)p0 * 256], B0 = pq[(size_t)c0 * 256];
            const float4 A1 = pq[(size_t)p1 * 256], B1 = pq[(size_t)c1 * 256];
            const float4 A2 = pq[(size_t)p2 * 256], B2 = pq[(size_t)c2 * 256];
            const float4 A3 = pq[(size_t)p3 * 256], B3 = pq[(size_t)c3 * 256];
            recs += sqdiff4(A0, B0);
            recs += sqdiff4(A1, B1);
            recs += sqdiff4(A2, B2);
            recs += sqdiff4(A3, B3);
        }
        // tail k = 12,13,14 (14 masked: e = ebase + 28672 may be >= NE)
        {
            const int e0 = ebase + 12 * EGRP;
            const int e1 = ebase + 13 * EGRP;
            const int e2 = ebase + 14 * EGRP;
            const bool v2 = e2 < NE;
            const int ec2 = v2 ? e2 : 0;
            const int p0 = pidx[e0],  c0 = cidx[e0];
            const int p1 = pidx[e1],  c1 = cidx[e1];
            const int p2 = pidx[ec2], c2 = cidx[ec2];
            const float4 A0 = pq[(size_t)p0 * 256], B0 = pq[(size_t)c0 * 256];
            const float4 A1 = pq[(size_t)p1 * 256], B1 = pq[(size_t)c1 * 256];
            const float4 A2 = pq[(size_t)p2 * 256], B2 = pq[(size_t)c2 * 256];
            recs += sqdiff4(A0, B0);
            recs += sqdiff4(A1, B1);
            recs += v2 ? sqdiff4(A2, B2) : 0.f;
        }
    }

    const float rb = blockReduceSum1024(bces);
    const float rr = blockReduceSum1024(recs);
    const float rp = blockReduceSum1024(ps);
    if (tid == 0) {
        slots[bid]              = (double)rb;
        slots[BLOCKS + bid]     = (double)rr;
        slots[2 * BLOCKS + bid] = (double)rp;
    }
}

// finalize: sum the 3 slot arrays, combine, write scalar
__global__ void fin_kernel(const double* __restrict__ slots,
                           float* __restrict__ out) {
    double sb = 0.0, sr = 0.0, sp = 0.0;
    for (int i = threadIdx.x; i < BLOCKS; i += 256) {
        sb += slots[i];
        sr += slots[BLOCKS + i];
        sp += slots[2 * BLOCKS + i];
    }
    sb = blockReduceSumD256(sb);
    sr = blockReduceSumD256(sr);
    sp = blockReduceSumD256(sp);
    if (threadIdx.x == 0) {
        const double bce = sb * (1.0 / ((double)NB * (double)NLAB));
        out[0] = (float)(bce + 5e-5 * sr + 1e-4 * sp);
    }
}

extern "C" void kernel_launch(void* const* d_in, const int* in_sizes, int n_in,
                              void* d_out, int out_size, void* d_ws, size_t ws_size,
                              hipStream_t stream) {
    const float* logits  = (const float*)d_in[0];
    const float* targets = (const float*)d_in[1];
    const float* params  = (const float*)d_in[2];
    const int*   pidx    = (const int*)d_in[3];
    const int*   cidx    = (const int*)d_in[4];
    double* slots = (double*)d_ws;
    float*  out   = (float*)d_out;

    fused_kernel<<<BLOCKS, 1024, 0, stream>>>(
        (const float4*)logits, (const float4*)targets, (const float4*)params,
        pidx, cidx, slots);
    fin_kernel<<<1, 256, 0, stream>>>(slots, out);
}

// Round 8
// 238.391 us; speedup vs baseline: 1.2557x; 1.2557x over previous
//
#include <hip/hip_runtime.h>
#include <hip/hip_fp16.h>

#define NLAB 30000
#define HID  1024
#define NB   256
#define NE   (NLAB - 1)

#define BLOCKS 512               // 2 per CU (LDS-limited), all identical
#define NL4 (NLAB / 4)           // 7500 float4 per row
#define HALF4 (NL4 / 2)          // 3750
#define EHALF 15000              // edge split point between the 2 row-sharers
#define SLOTE 7                  // edges staged per round (7 x 8KB = 56KB)

typedef const __attribute__((address_space(1))) void* gas1_t;
typedef __attribute__((address_space(3))) void* las3_t;

// async 16B/lane global->LDS DMA: wave loads 1KB contiguous, no VGPR data
__device__ __forceinline__ void gl_lds16(const void* g, void* l) {
    __builtin_amdgcn_global_load_lds((gas1_t)g, (las3_t)l, 16, 0, 0);
}

// float block reduce, 1024 threads (16 waves)
__device__ __forceinline__ float blockReduceSum1024(float v) {
#pragma unroll
    for (int off = 32; off > 0; off >>= 1)
        v += __shfl_down(v, off, 64);
    __shared__ float smr[16];
    const int lane = threadIdx.x & 63;
    const int wid  = threadIdx.x >> 6;
    __syncthreads();
    if (lane == 0) smr[wid] = v;
    __syncthreads();
    float r = 0.f;
    if (threadIdx.x == 0) {
#pragma unroll
        for (int i = 0; i < 16; ++i) r += smr[i];
    }
    return r;
}

__device__ __forceinline__ double blockReduceSumD256(double v) {
#pragma unroll
    for (int off = 32; off > 0; off >>= 1)
        v += __shfl_down(v, off, 64);
    __shared__ double smd[4];
    const int lane = threadIdx.x & 63;
    const int wid  = threadIdx.x >> 6;
    __syncthreads();
    if (lane == 0) smd[wid] = v;
    __syncthreads();
    double r = 0.0;
    if (threadIdx.x == 0) r = smd[0] + smd[1] + smd[2] + smd[3];
    return r;
}

__device__ __forceinline__ float sqdiff4(const float4 a, const float4 b) {
    const float dx = a.x - b.x, dy = a.y - b.y;
    const float dz = a.z - b.z, dw = a.w - b.w;
    return dx * dx + dy * dy + dz * dz + dw * dw;
}

// ---------------------------------------------------------------------------
// All 512 blocks identical:
//   row phase (R5-proven): block pair (r=bid>>1, h=bid&1) stages FULL fp16
//     sigmoid row in LDS (60 KB), BCE over its half of targets, prob_reg
//     over its half of edges from LDS.
//   rec phase: REUSES the 60 KB LDS as a DMA staging buffer. Rounds of 7
//     edges: 56 x 1KB global_load_lds (in-flight data lives in the DMA
//     queue, not VGPRs -> no spill, ~112 KB/CU outstanding), __syncthreads
//     (drains vmcnt), then 1024 threads compute sqdiffs from LDS.
// ---------------------------------------------------------------------------
__global__ __launch_bounds__(1024, 2)
void fused_kernel(const float4* __restrict__ lg4,
                  const float4* __restrict__ tg4,
                  const float* __restrict__ params,
                  const int* __restrict__ pidx,
                  const int* __restrict__ cidx,
                  double* __restrict__ slots) {
    __shared__ __attribute__((aligned(16))) char smem[SLOTE * 8192]; // 57344B >= 60000? no: see below
    // NOTE: need max(60000, 57344) bytes. Use 60416 to cover sprob.
    // (static assert via array size below)
    __shared__ __attribute__((aligned(16))) char smem2[60416 - SLOTE * 8192];
    (void)smem2; // smem and smem2 are adjacent in LDS; we only index smem for
                 // staging (57344B) and sprob spans both via the cast below.
    __half* sprob = (__half*)smem;        // 30000 halves = 60000 B
    float4* stg   = (float4*)smem;        // 7 slots x 512 float4 (p:256, c:256)

    const int tid  = threadIdx.x;
    const int bid  = blockIdx.x;
    const int lane = tid & 63;
    const int r    = bid >> 1;    // batch row
    const int h    = bid & 1;     // which half of targets/edges

    float bces = 0.f, recs = 0.f, ps = 0.f;

    // ---- row phase: sigmoid staging (full row) + BCE (half) ----
    {
        const float4* lrow = lg4 + (size_t)r * NL4;
        const float4* trow = tg4 + (size_t)r * NL4;
        const int tlo = h * HALF4, thi = tlo + HALF4;
        for (int i = tid; i < NL4; i += 1024) {
            const float4 l = lrow[i];
            const float e0 = __expf(-fabsf(l.x)), i0 = __frcp_rn(1.f + e0);
            const float e1 = __expf(-fabsf(l.y)), i1 = __frcp_rn(1.f + e1);
            const float e2 = __expf(-fabsf(l.z)), i2 = __frcp_rn(1.f + e2);
            const float e3 = __expf(-fabsf(l.w)), i3 = __frcp_rn(1.f + e3);
            const float s0 = l.x > 0.f ? i0 : 1.f - i0;
            const float s1 = l.y > 0.f ? i1 : 1.f - i1;
            const float s2 = l.z > 0.f ? i2 : 1.f - i2;
            const float s3 = l.w > 0.f ? i3 : 1.f - i3;
            sprob[4 * i + 0] = __float2half(s0);
            sprob[4 * i + 1] = __float2half(s1);
            sprob[4 * i + 2] = __float2half(s2);
            sprob[4 * i + 3] = __float2half(s3);
            if (i >= tlo && i < thi) {
                const float4 t = trow[i];
                bces += fmaxf(l.x, 0.f) - __logf(i0) - l.x * t.x;
                bces += fmaxf(l.y, 0.f) - __logf(i1) - l.y * t.y;
                bces += fmaxf(l.z, 0.f) - __logf(i2) - l.z * t.z;
                bces += fmaxf(l.w, 0.f) - __logf(i3) - l.w * t.w;
            }
        }
        __syncthreads();
        const int elo = h ? EHALF : 0;
        const int ehi = h ? NE : EHALF;
        for (int e = elo + tid; e < ehi; e += 1024) {
            const float d = __half2float(sprob[cidx[e]]) -
                            __half2float(sprob[pidx[e]]);
            ps += d > 0.f ? d : 0.f;
        }
    }

    // ---- rec phase: DMA-staged rounds over this block's edges ----
    {
        __syncthreads();  // prob phase done reading sprob; LDS now staging
        const int K    = (NE - bid + BLOCKS - 1) / BLOCKS;  // edges this block
        const int w    = __builtin_amdgcn_readfirstlane(tid >> 6); // wave 0..15
        const int NRND = (K + SLOTE - 1) / SLOTE;
        for (int t = 0; t < NRND; ++t) {
            // issue: 56 chunk-loads; wave w takes L = w, w+16, w+32, w+48
            for (int L = w; L < SLOTE * 8; L += 16) {
                const int u  = L >> 3;          // edge slot 0..6
                const int ch = L & 7;           // chunk: 0-3 p-row, 4-7 c-row
                const int k  = t * SLOTE + u;
                if (k < K) {
                    const int e   = bid + k * BLOCKS;
                    const int row = (ch < 4) ? pidx[e] : cidx[e];
                    const char* g = (const char*)params +
                                    (size_t)row * (HID * 4) +
                                    (ch & 3) * 1024 + lane * 16;
                    char* l = smem + u * 8192 + ch * 1024;  // wave-uniform base
                    gl_lds16(g, l);
                }
            }
            __syncthreads();   // drains vmcnt: all 56KB staged
            // compute: 7 edges x 256 float4-pairs = 1792 items
            for (int i = tid; i < SLOTE * 256; i += 1024) {
                const int u = i >> 8, f = i & 255;
                const int k = t * SLOTE + u;
                if (k < K) {
                    const float4 a = stg[u * 512 + f];
                    const float4 b = stg[u * 512 + 256 + f];
                    recs += sqdiff4(a, b);
                }
            }
            __syncthreads();   // before next round's DMA overwrites
        }
    }

    const float rb = blockReduceSum1024(bces);
    const float rr = blockReduceSum1024(recs);
    const float rp = blockReduceSum1024(ps);
    if (tid == 0) {
        slots[bid]              = (double)rb;
        slots[BLOCKS + bid]     = (double)rr;
        slots[2 * BLOCKS + bid] = (double)rp;
    }
}

// finalize: sum the 3 slot arrays, combine, write scalar
__global__ void fin_kernel(const double* __restrict__ slots,
                           float* __restrict__ out) {
    double sb = 0.0, sr = 0.0, sp = 0.0;
    for (int i = threadIdx.x; i < BLOCKS; i += 256) {
        sb += slots[i];
        sr += slots[BLOCKS + i];
        sp += slots[2 * BLOCKS + i];
    }
    sb = blockReduceSumD256(sb);
    sr = blockReduceSumD256(sr);
    sp = blockReduceSumD256(sp);
    if (threadIdx.x == 0) {
        const double bce = sb * (1.0 / ((double)NB * (double)NLAB));
        out[0] = (float)(bce + 5e-5 * sr + 1e-4 * sp);
    }
}

extern "C" void kernel_launch(void* const* d_in, const int* in_sizes, int n_in,
                              void* d_out, int out_size, void* d_ws, size_t ws_size,
                              hipStream_t stream) {
    const float* logits  = (const float*)d_in[0];
    const float* targets = (const float*)d_in[1];
    const float* params  = (const float*)d_in[2];
    const int*   pidx    = (const int*)d_in[3];
    const int*   cidx    = (const int*)d_in[4];
    double* slots = (double*)d_ws;
    float*  out   = (float*)d_out;

    fused_kernel<<<BLOCKS, 1024, 0, stream>>>(
        (const float4*)logits, (const float4*)targets, params,
        pidx, cidx, slots);
    fin_kernel<<<1, 256, 0, stream>>>(slots, out);
}

// Round 9
// 237.487 us; speedup vs baseline: 1.2605x; 1.0038x over previous
//
#include <hip/hip_runtime.h>
#include <hip/hip_fp16.h>

#define NLAB 30000
#define HID  1024
#define NB   256
#define NE   (NLAB - 1)

#define RECB   256               // rec-specialist blocks (start gathering at t=0)
#define ROWB   256               // row blocks (one full batch row each)
#define BLOCKS (RECB + ROWB)
#define NL4    (NLAB / 4)        // 7500 float4 per row
#define SLOTE  7                 // edges staged per DMA round (7 x 8KB = 56KB)
#define EREC   19456             // edges owned by rec blocks (76 per block exactly)
// row blocks own NE-EREC = 10543 edges: block j takes e = EREC+j+256m

typedef const __attribute__((address_space(1))) void* gas1_t;
typedef __attribute__((address_space(3))) void* las3_t;

__device__ __forceinline__ void gl_lds16(const void* g, void* l) {
    __builtin_amdgcn_global_load_lds((gas1_t)g, (las3_t)l, 16, 0, 0);
}

// float block reduce, 1024 threads (16 waves)
__device__ __forceinline__ float blockReduceSum1024(float v) {
#pragma unroll
    for (int off = 32; off > 0; off >>= 1)
        v += __shfl_down(v, off, 64);
    __shared__ float smr[16];
    const int lane = threadIdx.x & 63;
    const int wid  = threadIdx.x >> 6;
    __syncthreads();
    if (lane == 0) smr[wid] = v;
    __syncthreads();
    float r = 0.f;
    if (threadIdx.x == 0) {
#pragma unroll
        for (int i = 0; i < 16; ++i) r += smr[i];
    }
    return r;
}

__device__ __forceinline__ double blockReduceSumD256(double v) {
#pragma unroll
    for (int off = 32; off > 0; off >>= 1)
        v += __shfl_down(v, off, 64);
    __shared__ double smd[4];
    const int lane = threadIdx.x & 63;
    const int wid  = threadIdx.x >> 6;
    __syncthreads();
    if (lane == 0) smd[wid] = v;
    __syncthreads();
    double r = 0.0;
    if (threadIdx.x == 0) r = smd[0] + smd[1] + smd[2] + smd[3];
    return r;
}

__device__ __forceinline__ float sqdiff4(const float4 a, const float4 b) {
    const float dx = a.x - b.x, dy = a.y - b.y;
    const float dz = a.z - b.z, dw = a.w - b.w;
    return dx * dx + dy * dy + dz * dz + dw * dw;
}

// R7-proven DMA-staged gather rounds: edges e = ebase + k*256, k < K.
// smem used as 7 x 8KB staging slots; in-flight data lives in the DMA queue.
__device__ __forceinline__ float rec_rounds(const float* __restrict__ params,
                                            const int* __restrict__ pidx,
                                            const int* __restrict__ cidx,
                                            char* smem, int ebase, int K,
                                            int tid, int lane) {
    float recs = 0.f;
    float4* stg = (float4*)smem;
    const int w = __builtin_amdgcn_readfirstlane(tid >> 6);   // wave 0..15
    const int NRND = (K + SLOTE - 1) / SLOTE;
    for (int t = 0; t < NRND; ++t) {
        // issue 56 x 1KB chunk DMAs; wave w takes L = w, w+16, w+32, w+48
        for (int L = w; L < SLOTE * 8; L += 16) {
            const int u  = L >> 3;           // edge slot 0..6
            const int ch = L & 7;            // 0-3 p-row quarters, 4-7 c-row
            const int k  = t * SLOTE + u;
            if (k < K) {
                const int e   = ebase + k * 256;
                const int row = (ch < 4) ? pidx[e] : cidx[e];
                const char* g = (const char*)params + (size_t)row * (HID * 4) +
                                (ch & 3) * 1024 + lane * 16;
                gl_lds16(g, smem + u * 8192 + ch * 1024);    // uniform base ✓
            }
        }
        __syncthreads();   // drains vmcnt: 56KB staged
        for (int i = tid; i < SLOTE * 256; i += 1024) {
            const int u = i >> 8, f = i & 255;
            if (t * SLOTE + u < K)
                recs += sqdiff4(stg[u * 512 + f], stg[u * 512 + 256 + f]);
        }
        __syncthreads();   // before next round's DMA overwrites
    }
    return recs;
}

// ---------------------------------------------------------------------------
// Phase-parallel specialization:
//   blocks [0,256):   rec specialists — gather from t=0. 76 edges each
//                     (e = bid + k*256 < 19456), 11 DMA rounds.
//   blocks [256,512): row blocks — full batch row r=bid-256: BCE + fp16
//                     sigmoid row in LDS + prob over ALL edges; then reuse
//                     LDS as staging and take edges e = 19456+j+k*256 (~42).
// The row/prob work (streaming+LDS, ~16us) overlaps the long gather.
// ---------------------------------------------------------------------------
__global__ __launch_bounds__(1024, 2)
void fused_kernel(const float4* __restrict__ lg4,
                  const float4* __restrict__ tg4,
                  const float* __restrict__ params,
                  const int* __restrict__ pidx,
                  const int* __restrict__ cidx,
                  double* __restrict__ slots) {
    __shared__ __attribute__((aligned(16))) char smem[60032];
    __half* sprob = (__half*)smem;    // 30000 halves = 60000 B (row blocks)

    const int tid  = threadIdx.x;
    const int bid  = blockIdx.x;
    const int lane = tid & 63;

    float bces = 0.f, recs = 0.f, ps = 0.f;

    if (bid < RECB) {
        // ---- rec specialist: gather immediately ----
        recs = rec_rounds(params, pidx, cidx, smem, bid, EREC / RECB, tid, lane);
    } else {
        const int j = bid - RECB;     // row index / edge-tail sub-index
        // ---- row phase: full-row sigmoid staging + BCE ----
        {
            const float4* lrow = lg4 + (size_t)j * NL4;
            const float4* trow = tg4 + (size_t)j * NL4;
            for (int i = tid; i < NL4; i += 1024) {
                const float4 l = lrow[i];
                const float4 t = trow[i];
                const float e0 = __expf(-fabsf(l.x)), i0 = __frcp_rn(1.f + e0);
                const float e1 = __expf(-fabsf(l.y)), i1 = __frcp_rn(1.f + e1);
                const float e2 = __expf(-fabsf(l.z)), i2 = __frcp_rn(1.f + e2);
                const float e3 = __expf(-fabsf(l.w)), i3 = __frcp_rn(1.f + e3);
                const float s0 = l.x > 0.f ? i0 : 1.f - i0;
                const float s1 = l.y > 0.f ? i1 : 1.f - i1;
                const float s2 = l.z > 0.f ? i2 : 1.f - i2;
                const float s3 = l.w > 0.f ? i3 : 1.f - i3;
                sprob[4 * i + 0] = __float2half(s0);
                sprob[4 * i + 1] = __float2half(s1);
                sprob[4 * i + 2] = __float2half(s2);
                sprob[4 * i + 3] = __float2half(s3);
                // softplus(l) = max(l,0) - log(sigmoid(|l|))
                bces += fmaxf(l.x, 0.f) - __logf(i0) - l.x * t.x;
                bces += fmaxf(l.y, 0.f) - __logf(i1) - l.y * t.y;
                bces += fmaxf(l.z, 0.f) - __logf(i2) - l.z * t.z;
                bces += fmaxf(l.w, 0.f) - __logf(i3) - l.w * t.w;
            }
            __syncthreads();
            // ---- prob_reg over ALL edges from LDS ----
            for (int e = tid; e < NE; e += 1024) {
                const float d = __half2float(sprob[cidx[e]]) -
                                __half2float(sprob[pidx[e]]);
                ps += d > 0.f ? d : 0.f;
            }
            __syncthreads();   // done reading sprob; LDS becomes staging
        }
        // ---- rec tail: edges e = EREC + j + k*256 ----
        const int K = (NE - EREC - j + 255) / 256;   // 42 (j<47) or 41
        recs = rec_rounds(params, pidx, cidx, smem, EREC + j, K, tid, lane);
    }

    const float rb = blockReduceSum1024(bces);
    const float rr = blockReduceSum1024(recs);
    const float rp = blockReduceSum1024(ps);
    if (tid == 0) {
        slots[bid]              = (double)rb;
        slots[BLOCKS + bid]     = (double)rr;
        slots[2 * BLOCKS + bid] = (double)rp;
    }
}

// finalize: sum the 3 slot arrays, combine, write scalar
__global__ void fin_kernel(const double* __restrict__ slots,
                           float* __restrict__ out) {
    double sb = 0.0, sr = 0.0, sp = 0.0;
    for (int i = threadIdx.x; i < BLOCKS; i += 256) {
        sb += slots[i];
        sr += slots[BLOCKS + i];
        sp += slots[2 * BLOCKS + i];
    }
    sb = blockReduceSumD256(sb);
    sr = blockReduceSumD256(sr);
    sp = blockReduceSumD256(sp);
    if (threadIdx.x == 0) {
        const double bce = sb * (1.0 / ((double)NB * (double)NLAB));
        out[0] = (float)(bce + 5e-5 * sr + 1e-4 * sp);
    }
}

extern "C" void kernel_launch(void* const* d_in, const int* in_sizes, int n_in,
                              void* d_out, int out_size, void* d_ws, size_t ws_size,
                              hipStream_t stream) {
    const float* logits  = (const float*)d_in[0];
    const float* targets = (const float*)d_in[1];
    const float* params  = (const float*)d_in[2];
    const int*   pidx    = (const int*)d_in[3];
    const int*   cidx    = (const int*)d_in[4];
    double* slots = (double*)d_ws;
    float*  out   = (float*)d_out;

    fused_kernel<<<BLOCKS, 1024, 0, stream>>>(
        (const float4*)logits, (const float4*)targets, params,
        pidx, cidx, slots);
    fin_kernel<<<1, 256, 0, stream>>>(slots, out);
}